// Round 2
// baseline (769.298 us; speedup 1.0000x reference)
//
#include <hip/hip_runtime.h>

// ---------------------------------------------------------------------------
// GIN forward on MI355X.
// Pipeline: CSR build -> [agg -> GEMM(s) w/ fused bias/relu/BN] x3 -> head.
// GEMMs use bf16x3 split-precision MFMA (A_hi*W_hi + A_lo*W_hi + A_hi*W_lo)
// to reach ~fp32 accuracy while using the 16x16x32 bf16 matrix cores.
// ---------------------------------------------------------------------------

constexpr int NN  = 100000;   // nodes
constexpr int NE  = 1600000;  // edges
constexpr int DIN = 64;
constexpr int HID = 128;

typedef __attribute__((ext_vector_type(4))) float f32x4;
typedef __attribute__((ext_vector_type(8))) short bf16x8;

__device__ __forceinline__ short f2bf(float f) {
    union { float f; unsigned u; } x; x.f = f;
    unsigned r = x.u + 0x7fffu + ((x.u >> 16) & 1u);   // RNE
    return (short)(r >> 16);
}
__device__ __forceinline__ float bf2f(short s) {
    union { unsigned u; float f; } x; x.u = ((unsigned)(unsigned short)s) << 16;
    return x.f;
}

// ---------------------------------------------------------------- CSR build
__global__ void hist_kernel(const int* __restrict__ eidx, int* __restrict__ deg) {
    int e = blockIdx.x * 256 + threadIdx.x;
    if (e < NE) atomicAdd(&deg[eidx[NE + e]], 1);
}

__global__ void scan1_kernel(const int* __restrict__ deg, int* __restrict__ offs,
                             int* __restrict__ bsum) {
    __shared__ int lds[512];
    int t = threadIdx.x;
    int i = blockIdx.x * 512 + t;
    int v = (i < NN) ? deg[i] : 0;
    lds[t] = v; __syncthreads();
    #pragma unroll
    for (int o = 1; o < 512; o <<= 1) {
        int x = (t >= o) ? lds[t - o] : 0;
        __syncthreads();
        lds[t] += x;
        __syncthreads();
    }
    if (i < NN) offs[i] = lds[t] - v;          // exclusive
    if (t == 511) bsum[blockIdx.x] = lds[511]; // block total
}

__global__ void scan2_kernel(int* __restrict__ bsum, int nb) {
    __shared__ int lds[256];
    int t = threadIdx.x;
    int v = (t < nb) ? bsum[t] : 0;
    lds[t] = v; __syncthreads();
    #pragma unroll
    for (int o = 1; o < 256; o <<= 1) {
        int x = (t >= o) ? lds[t - o] : 0;
        __syncthreads();
        lds[t] += x;
        __syncthreads();
    }
    if (t < nb) bsum[t] = lds[t] - v;          // exclusive block base
}

__global__ void scan3_kernel(int* __restrict__ offs, const int* __restrict__ bsum,
                             int* __restrict__ cursor) {
    int i = blockIdx.x * 512 + threadIdx.x;
    if (i < NN) {
        int val = offs[i] + bsum[blockIdx.x];
        offs[i] = val;
        cursor[i] = val;
    }
    if (i == 0) offs[NN] = NE;
}

__global__ void scatter_kernel(const int* __restrict__ eidx, int* __restrict__ cursor,
                               int* __restrict__ esrc) {
    int e = blockIdx.x * 256 + threadIdx.x;
    if (e < NE) {
        int d = eidx[NE + e];
        int p = atomicAdd(&cursor[d], 1);
        esrc[p] = eidx[e];
    }
}

// ---------------------------------------------------------------- aggregation
// out[n] = (1+eps)*h[n] + sum_{s in nbr(n)} h[s]   (D = 64 or 128, fp32)
template<int D>
__global__ void agg_kernel(const float* __restrict__ h, const int* __restrict__ offs,
                           const int* __restrict__ esrc, const float* __restrict__ epsp,
                           float* __restrict__ out) {
    constexpr int TPN = D / 4;                 // threads per node (float4 lanes)
    int node = blockIdx.x * (256 / TPN) + threadIdx.x / TPN;
    int f4   = threadIdx.x % TPN;
    if (node >= NN) return;
    const f32x4* h4 = (const f32x4*)h;
    float eps = 1.0f + *epsp;
    f32x4 acc = h4[(size_t)node * TPN + f4] * eps;
    int k  = offs[node];
    int k1 = offs[node + 1];
    int s_next = (k < k1) ? esrc[k] : 0;
    while (k < k1) {
        int s = s_next;
        ++k;
        if (k < k1) s_next = esrc[k];
        acc += h4[(size_t)s * TPN + f4];
    }
    ((f32x4*)out)[(size_t)node * TPN + f4] = acc;
}

// ---------------------------------------------------------------- weight pack
// Pack W[K][128] (fp32) into B-fragment order for mfma_f32_16x16x32_bf16,
// split hi/lo: P[0..T-1] = hi frags, P[T..2T-1] = lo frags, T=(K/32)*8*64.
// frag: P[c][nt][lane][j] = bf16( W[c*32 + (lane>>4)*8 + j][nt*16 + (lane&15)] )
template<int K>
__global__ void packw_kernel(const float* __restrict__ W, short* __restrict__ P) {
    constexpr int T = (K / 32) * 8 * 64;
    int idx = blockIdx.x * 256 + threadIdx.x;
    if (idx >= T) return;
    int c  = idx >> 9;
    int nt = (idx >> 6) & 7;
    int l  = idx & 63;
    int col   = nt * 16 + (l & 15);
    int kbase = c * 32 + (l >> 4) * 8;
    bf16x8 hi, lo;
    #pragma unroll
    for (int j = 0; j < 8; ++j) {
        float w = W[(kbase + j) * HID + col];
        short h = f2bf(w);
        hi[j] = h;
        lo[j] = f2bf(w - bf2f(h));
    }
    *(bf16x8*)&P[(size_t)idx * 8]       = hi;
    *(bf16x8*)&P[(size_t)(T + idx) * 8] = lo;
}

// ---------------------------------------------------------------- GEMM
// C[M,128] = epilogue(A[M,K] @ W[K,128])   via bf16x3 split products
// MODE 0: relu(.+bias)          -> out[M,128]
// MODE 1: bn(relu(.+bias))      -> out[M,128]
// MODE 2: head: dot(relu(.+bias), Wf) + bf -> out[M]
template<int K, int MODE>
__global__ __launch_bounds__(256)
void gemm_kernel(const float* __restrict__ A, const short* __restrict__ P,
                 const float* __restrict__ bias,
                 const float* __restrict__ g, const float* __restrict__ be,
                 const float* __restrict__ m, const float* __restrict__ v,
                 const float* __restrict__ Wf, const float* __restrict__ bf,
                 float* __restrict__ out, int M) {
    constexpr int NCH = K / 32;
    constexpr int T   = NCH * 8 * 64;          // frags per half (hi or lo)
    __shared__ short wlds[2 * T * 8];

    const int tid  = threadIdx.x;
    const int wid  = tid >> 6;
    const int lane = tid & 63;

    // stage packed W (hi then lo) to LDS, linear coalesced 16B
    for (int i = tid; i < 2 * T; i += 256)
        ((bf16x8*)wlds)[i] = ((const bf16x8*)P)[i];
    __syncthreads();

    const int rlo  = lane & 15;
    const int kgrp = lane >> 4;
    const int row  = blockIdx.x * 64 + wid * 16 + rlo;
    const int r    = row < M ? row : M - 1;
    const float* arow = A + (size_t)r * K + kgrp * 8;

    f32x4 acc[8];
    #pragma unroll
    for (int i = 0; i < 8; ++i) acc[i] = (f32x4)0.0f;

    #pragma unroll
    for (int c = 0; c < NCH; ++c) {
        f32x4 a0 = *(const f32x4*)(arow + c * 32);
        f32x4 a1 = *(const f32x4*)(arow + c * 32 + 4);
        bf16x8 ah, al;
        #pragma unroll
        for (int j = 0; j < 4; ++j) {
            short h0 = f2bf(a0[j]);
            short h1 = f2bf(a1[j]);
            ah[j]     = h0;
            ah[j + 4] = h1;
            al[j]     = f2bf(a0[j] - bf2f(h0));
            al[j + 4] = f2bf(a1[j] - bf2f(h1));
        }
        #pragma unroll
        for (int nt = 0; nt < 8; ++nt) {
            int fi = ((c * 8) + nt) * 64 + lane;
            bf16x8 wh = *(bf16x8*)&wlds[(size_t)fi * 8];
            bf16x8 wl = *(bf16x8*)&wlds[(size_t)(T + fi) * 8];
            acc[nt] = __builtin_amdgcn_mfma_f32_16x16x32_bf16(ah, wh, acc[nt], 0, 0, 0);
            acc[nt] = __builtin_amdgcn_mfma_f32_16x16x32_bf16(al, wh, acc[nt], 0, 0, 0);
            acc[nt] = __builtin_amdgcn_mfma_f32_16x16x32_bf16(ah, wl, acc[nt], 0, 0, 0);
        }
    }

    if constexpr (MODE == 2) {
        float p0 = 0, p1 = 0, p2 = 0, p3 = 0;
        #pragma unroll
        for (int nt = 0; nt < 8; ++nt) {
            int col  = nt * 16 + (lane & 15);
            float bb = bias[col];
            float wv = Wf[col];
            p0 += fmaxf(acc[nt][0] + bb, 0.f) * wv;
            p1 += fmaxf(acc[nt][1] + bb, 0.f) * wv;
            p2 += fmaxf(acc[nt][2] + bb, 0.f) * wv;
            p3 += fmaxf(acc[nt][3] + bb, 0.f) * wv;
        }
        #pragma unroll
        for (int o = 1; o < 16; o <<= 1) {
            p0 += __shfl_xor(p0, o);
            p1 += __shfl_xor(p1, o);
            p2 += __shfl_xor(p2, o);
            p3 += __shfl_xor(p3, o);
        }
        if ((lane & 15) == 0) {
            int rbase = blockIdx.x * 64 + wid * 16 + kgrp * 4;
            float bfv = bf[0];
            if (rbase + 0 < M) out[rbase + 0] = p0 + bfv;
            if (rbase + 1 < M) out[rbase + 1] = p1 + bfv;
            if (rbase + 2 < M) out[rbase + 2] = p2 + bfv;
            if (rbase + 3 < M) out[rbase + 3] = p3 + bfv;
        }
    } else {
        #pragma unroll
        for (int nt = 0; nt < 8; ++nt) {
            int col  = nt * 16 + (lane & 15);
            float bb = bias[col];
            float s = 1.f, t = 0.f;
            if constexpr (MODE == 1) {
                float sv = g[col] * rsqrtf(v[col] + 1e-5f);
                s = sv; t = be[col] - m[col] * sv;
            }
            #pragma unroll
            for (int jj = 0; jj < 4; ++jj) {
                int rr = blockIdx.x * 64 + wid * 16 + kgrp * 4 + jj;
                float val = fmaxf(acc[nt][jj] + bb, 0.f);
                if constexpr (MODE == 1) val = val * s + t;
                if (rr < M) out[(size_t)rr * 128 + col] = val;
            }
        }
    }
}

// ---------------------------------------------------------------------------
extern "C" void kernel_launch(void* const* d_in, const int* in_sizes, int n_in,
                              void* d_out, int out_size, void* d_ws, size_t ws_size,
                              hipStream_t stream) {
    const float* x    = (const float*)d_in[0];
    const int*   eidx = (const int*)d_in[1];
    const float* eps1 = (const float*)d_in[2];
    const float* W1a  = (const float*)d_in[3];
    const float* b1a  = (const float*)d_in[4];
    const float* W1b  = (const float*)d_in[5];
    const float* b1b  = (const float*)d_in[6];
    const float* g1   = (const float*)d_in[7];
    const float* be1  = (const float*)d_in[8];
    const float* m1   = (const float*)d_in[9];
    const float* v1   = (const float*)d_in[10];
    const float* eps2 = (const float*)d_in[11];
    const float* W2a  = (const float*)d_in[12];
    const float* b2a  = (const float*)d_in[13];
    const float* g2   = (const float*)d_in[14];
    const float* be2  = (const float*)d_in[15];
    const float* m2   = (const float*)d_in[16];
    const float* v2   = (const float*)d_in[17];
    const float* eps3 = (const float*)d_in[18];
    const float* W3a  = (const float*)d_in[19];
    const float* b3a  = (const float*)d_in[20];
    const float* W3b  = (const float*)d_in[21];
    const float* b3b  = (const float*)d_in[22];
    const float* g3   = (const float*)d_in[23];
    const float* be3  = (const float*)d_in[24];
    const float* m3   = (const float*)d_in[25];
    const float* v3   = (const float*)d_in[26];
    const float* Wl   = (const float*)d_in[27];
    const float* bl   = (const float*)d_in[28];
    const float* Wf   = (const float*)d_in[29];
    const float* bfp  = (const float*)d_in[30];

    char* ws = (char*)d_ws;
    size_t off = 0;
    auto alloc = [&](size_t bytes) -> void* {
        off = (off + 255) & ~(size_t)255;
        void* p = ws + off;
        off += bytes;
        return p;
    };

    float* bufA   = (float*)alloc((size_t)NN * 128 * 4);
    float* bufB   = (float*)alloc((size_t)NN * 128 * 4);
    int*   deg    = (int*)alloc((size_t)NN * 4);
    int*   offs   = (int*)alloc((size_t)(NN + 1) * 4);
    int*   cursor = (int*)alloc((size_t)NN * 4);
    int*   esrc   = (int*)alloc((size_t)NE * 4);
    int*   bsum   = (int*)alloc(256 * 4);
    short* P1a    = (short*)alloc((size_t)2 * DIN * HID * 2);
    short* P1b    = (short*)alloc((size_t)2 * HID * HID * 2);
    short* P2a    = (short*)alloc((size_t)2 * HID * HID * 2);
    short* P3a    = (short*)alloc((size_t)2 * HID * HID * 2);
    short* P3b    = (short*)alloc((size_t)2 * HID * HID * 2);
    short* Pl     = (short*)alloc((size_t)2 * HID * HID * 2);

    const int NB_SCAN = (NN + 511) / 512;           // 196
    const int GRID_E  = (NE + 255) / 256;           // 6250
    const int GRID_G  = (NN + 63) / 64;             // 1563 (GEMM, 64 rows/block)
    const int GRID_A64  = NN / 16;                  // 6250
    const int GRID_A128 = NN / 8;                   // 12500

    // ---- CSR build
    hipMemsetAsync(deg, 0, (size_t)NN * 4, stream);
    hist_kernel<<<GRID_E, 256, 0, stream>>>(eidx, deg);
    scan1_kernel<<<NB_SCAN, 512, 0, stream>>>(deg, offs, bsum);
    scan2_kernel<<<1, 256, 0, stream>>>(bsum, NB_SCAN);
    scan3_kernel<<<NB_SCAN, 512, 0, stream>>>(offs, bsum, cursor);
    scatter_kernel<<<GRID_E, 256, 0, stream>>>(eidx, cursor, esrc);

    // ---- pack weights (bf16 hi/lo B-fragment order)
    packw_kernel<64><<<4, 256, 0, stream>>>(W1a, P1a);
    packw_kernel<128><<<8, 256, 0, stream>>>(W1b, P1b);
    packw_kernel<128><<<8, 256, 0, stream>>>(W2a, P2a);
    packw_kernel<128><<<8, 256, 0, stream>>>(W3a, P3a);
    packw_kernel<128><<<8, 256, 0, stream>>>(W3b, P3b);
    packw_kernel<128><<<8, 256, 0, stream>>>(Wl, Pl);

    // ---- layer 1
    agg_kernel<64><<<GRID_A64, 256, 0, stream>>>(x, offs, esrc, eps1, bufA);
    gemm_kernel<64, 0><<<GRID_G, 256, 0, stream>>>(bufA, P1a, b1a, nullptr, nullptr,
                                                   nullptr, nullptr, nullptr, nullptr,
                                                   bufB, NN);
    gemm_kernel<128, 1><<<GRID_G, 256, 0, stream>>>(bufB, P1b, b1b, g1, be1, m1, v1,
                                                    nullptr, nullptr, bufA, NN);
    // ---- layer 2
    agg_kernel<128><<<GRID_A128, 256, 0, stream>>>(bufA, offs, esrc, eps2, bufB);
    gemm_kernel<128, 1><<<GRID_G, 256, 0, stream>>>(bufB, P2a, b2a, g2, be2, m2, v2,
                                                    nullptr, nullptr, bufA, NN);
    // ---- layer 3
    agg_kernel<128><<<GRID_A128, 256, 0, stream>>>(bufA, offs, esrc, eps3, bufB);
    gemm_kernel<128, 0><<<GRID_G, 256, 0, stream>>>(bufB, P3a, b3a, nullptr, nullptr,
                                                    nullptr, nullptr, nullptr, nullptr,
                                                    bufA, NN);
    gemm_kernel<128, 1><<<GRID_G, 256, 0, stream>>>(bufA, P3b, b3b, g3, be3, m3, v3,
                                                    nullptr, nullptr, bufB, NN);
    // ---- head (Wl + Wf fused)
    gemm_kernel<128, 2><<<GRID_G, 256, 0, stream>>>(bufB, Pl, bl, nullptr, nullptr,
                                                    nullptr, nullptr, Wf, bfp,
                                                    (float*)d_out, NN);
}